// Round 5
// baseline (544.280 us; speedup 1.0000x reference)
//
#include <hip/hip_runtime.h>
#include <hip/hip_bf16.h>

// Problem constants (fixed by the reference)
constexpr int N_NODES = 50000;
constexpr int N_EDGES = 800000;
constexpr int R_REL   = 8;
constexpr int BASES   = 4;
constexpr int D       = 256;                 // DIN = DH = DOUT
constexpr int KT      = BASES * D + D;       // 1280: 4 basis blocks + self block
constexpr int NKEYS   = N_NODES * R_REL;     // 400000 (dst,rel) buckets
// z layout: k < 1024 -> k = col*4 + b (basis-space aggregate, interleaved)
//           k >= 1024 -> self feature col = k - 1024

typedef __attribute__((ext_vector_type(8))) short bf16x8;
typedef __attribute__((ext_vector_type(4))) float f32x4;

__device__ inline float bfu_lo(unsigned u) { return __uint_as_float(u << 16); }
__device__ inline float bfu_hi(unsigned u) { return __uint_as_float(u & 0xFFFF0000u); }
__device__ inline unsigned short f2bu(float f) {
  __hip_bfloat16 h = __float2bfloat16(f);
  return *reinterpret_cast<unsigned short*>(&h);
}
__device__ inline void store_out(float* p, float v) { *p = v; }
__device__ inline void store_out(__hip_bfloat16* p, float v) { *p = __float2bfloat16(v); }

// async 16B global -> LDS (wave-uniform lds base + lane*16)
__device__ inline void gload_lds16(void* lds, const void* g) {
  __builtin_amdgcn_global_load_lds(
      (const __attribute__((address_space(1))) unsigned*)g,
      (__attribute__((address_space(3))) unsigned*)lds, 16, 0, 0);
}

// ---------------------------------------------------------------------------
// 1. Count per-(dst,rel) edges AND record each edge's rank within its bucket
//    (single atomic pass; bucket placement later needs no atomics).
// ---------------------------------------------------------------------------
__global__ __launch_bounds__(256) void count_rank_kernel(
    const int* __restrict__ ei, const int* __restrict__ et,
    int* __restrict__ cnt, int* __restrict__ rank) {
  int e = blockIdx.x * 256 + threadIdx.x;
  if (e < N_EDGES) {
    int dst = ei[N_EDGES + e];
    int rt  = et[e];
    rank[e] = atomicAdd(&cnt[dst * R_REL + rt], 1);
  }
}

// ---------------------------------------------------------------------------
// 2. Exclusive scan of cnt[400000] -> ecdf (3-phase).
//    ecdf[n*8] doubles as the node's edge start (buckets are ordered).
// ---------------------------------------------------------------------------
constexpr int SCAN_B = (NKEYS + 255) / 256;            // 1563 blocks
constexpr int CHUNK  = (SCAN_B + 255) / 256;           // 7 per thread in phaseB

__global__ __launch_bounds__(256) void scan_phaseA(
    const int* __restrict__ cnt, int* __restrict__ bsum) {
  __shared__ int sd[256];
  int tid = threadIdx.x;
  int idx = blockIdx.x * 256 + tid;
  int d = (idx < NKEYS) ? cnt[idx] : 0;
  sd[tid] = d;
  __syncthreads();
  for (int off = 128; off > 0; off >>= 1) {
    if (tid < off) sd[tid] += sd[tid + off];
    __syncthreads();
  }
  if (tid == 0) bsum[blockIdx.x] = sd[0];
}

__global__ __launch_bounds__(256) void scan_phaseB(
    const int* __restrict__ bsum, int* __restrict__ boff,
    int* __restrict__ ecdf) {
  __shared__ int sd[256];
  int tid = threadIdx.x;
  int loc[CHUNK];
  int lsum = 0;
#pragma unroll
  for (int j = 0; j < CHUNK; j++) {
    int i = tid * CHUNK + j;
    loc[j] = (i < SCAN_B) ? bsum[i] : 0;
    lsum += loc[j];
  }
  sd[tid] = lsum;
  __syncthreads();
  for (int off = 1; off < 256; off <<= 1) {
    int t = (tid >= off) ? sd[tid - off] : 0;
    __syncthreads();
    sd[tid] += t;
    __syncthreads();
  }
  int running = sd[tid] - lsum;  // exclusive prefix of this thread's chunk
#pragma unroll
  for (int j = 0; j < CHUNK; j++) {
    int i = tid * CHUNK + j;
    if (i < SCAN_B) boff[i] = running;
    running += loc[j];
  }
  if (tid == 0) ecdf[NKEYS] = N_EDGES;
}

// phase C also folds the per-(node,rel) basis-weight tables for both layers.
__global__ __launch_bounds__(256) void scan_phaseC_winv(
    const int* __restrict__ cnt, const int* __restrict__ boff,
    const float* __restrict__ comp1, const float* __restrict__ comp2,
    int* __restrict__ ecdf, float4* __restrict__ wtab1,
    float4* __restrict__ wtab2) {
  __shared__ int sd[256];
  int tid = threadIdx.x;
  int idx = blockIdx.x * 256 + tid;
  int d = (idx < NKEYS) ? cnt[idx] : 0;
  sd[tid] = d;
  __syncthreads();
  for (int off = 1; off < 256; off <<= 1) {
    int t = (tid >= off) ? sd[tid - off] : 0;
    __syncthreads();
    sd[tid] += t;
    __syncthreads();
  }
  if (idx < NKEYS) {
    ecdf[idx] = boff[blockIdx.x] + sd[tid] - d;
    int r = idx & 7;
    float inv = 1.0f / (float)(d > 0 ? d : 1);
    float4 c1 = *(const float4*)(comp1 + r * BASES);
    float4 c2 = *(const float4*)(comp2 + r * BASES);
    wtab1[idx] = make_float4(c1.x * inv, c1.y * inv, c1.z * inv, c1.w * inv);
    wtab2[idx] = make_float4(c2.x * inv, c2.y * inv, c2.z * inv, c2.w * inv);
  }
}

// ---------------------------------------------------------------------------
// 3. Bucket edges (no atomics): pos = ecdf[key] + rank[e]
// ---------------------------------------------------------------------------
__global__ __launch_bounds__(256) void bucket_kernel(
    const int* __restrict__ ei, const int* __restrict__ et,
    const int* __restrict__ rank, const int* __restrict__ ecdf,
    int* __restrict__ packed) {
  int e = blockIdx.x * 256 + threadIdx.x;
  if (e < N_EDGES) {
    int src = ei[e];
    int dst = ei[N_EDGES + e];
    int rt  = et[e];
    int pos = ecdf[dst * R_REL + rt] + rank[e];
    packed[pos] = src | (rt << 20);
  }
}

// ---------------------------------------------------------------------------
// 4. x (fp32) -> bf16, packed as uint pairs: x2[n*128 + c] holds cols 2c,2c+1
// ---------------------------------------------------------------------------
__global__ __launch_bounds__(256) void convert_kernel(
    const float* __restrict__ x, unsigned* __restrict__ x2) {
  int idx = blockIdx.x * 256 + threadIdx.x;  // over N*128
  if (idx < N_NODES * 128) {
    float2 v = *(const float2*)(x + (size_t)idx * 2);
    x2[idx] = (unsigned)f2bu(v.x) | ((unsigned)f2bu(v.y) << 16);
  }
}

// ---------------------------------------------------------------------------
// 5. Weight build: WT[o][k] bf16 (transposed). Coalesced reads, LDS transpose.
// ---------------------------------------------------------------------------
__global__ __launch_bounds__(256) void make_w_kernel(
    const float* __restrict__ basis, const float* __restrict__ root,
    __hip_bfloat16* __restrict__ WT) {
  __shared__ __hip_bfloat16 tile[64][256];
  int k0 = blockIdx.x * 64;
  int tid = threadIdx.x;
#pragma unroll 4
  for (int r = 0; r < 64; r++) {
    int k = k0 + r;
    const float* srow = (k < BASES * D)
        ? basis + ((size_t)(k & 3) * D + (k >> 2)) * D
        : root + (size_t)(k - BASES * D) * D;
    tile[r][tid] = __float2bfloat16(srow[tid]);
  }
  __syncthreads();
  __hip_bfloat16* dst = WT + (size_t)tid * KT + k0;
#pragma unroll
  for (int c = 0; c < 8; c++) {
    union { short s[8]; int4 v; } u;
#pragma unroll
    for (int r = 0; r < 8; r++)
      u.s[r] = *reinterpret_cast<short*>(&tile[c * 8 + r][tid]);
    *(int4*)(dst + c * 8) = u.v;
  }
}

// ---------------------------------------------------------------------------
// 6. Aggregate into basis space. WAVE per node, no LDS/barriers. Main loop
//    keeps 8 gathers in flight; clamped-4 tail.
// ---------------------------------------------------------------------------
__device__ inline void edge_fma(float acc[BASES][4], uint2 v, float4 w) {
  float a0 = bfu_lo(v.x), a1 = bfu_hi(v.x), a2 = bfu_lo(v.y), a3 = bfu_hi(v.y);
  acc[0][0] += w.x * a0; acc[0][1] += w.x * a1; acc[0][2] += w.x * a2; acc[0][3] += w.x * a3;
  acc[1][0] += w.y * a0; acc[1][1] += w.y * a1; acc[1][2] += w.y * a2; acc[1][3] += w.y * a3;
  acc[2][0] += w.z * a0; acc[2][1] += w.z * a1; acc[2][2] += w.z * a2; acc[2][3] += w.z * a3;
  acc[3][0] += w.w * a0; acc[3][1] += w.w * a1; acc[3][2] += w.w * a2; acc[3][3] += w.w * a3;
}

__global__ __launch_bounds__(256) void aggregate_kernel(
    const unsigned* __restrict__ x2,   // bf16 features as uint pairs [N][128]
    const int* __restrict__ packed,
    const int* __restrict__ ecdf,      // node n edges: [ecdf[8n], ecdf[8n+8])
    const float4* __restrict__ wtab,   // [N*8] per-(node,rel) basis weights
    __hip_bfloat16* __restrict__ zA)   // [N][KT]
{
  int tid = threadIdx.x;
  int wave = tid >> 6, lane = tid & 63;
  int n = blockIdx.x * 4 + wave;       // wave-uniform node
  const float4 wzero = make_float4(0.f, 0.f, 0.f, 0.f);

  float acc[BASES][4] = {};
  int s = ecdf[n * R_REL], e = ecdf[n * R_REL + R_REL];
  const float4* wt = wtab + (size_t)n * R_REL;
  int base = s;

  // main loop: 8 edges, 8 gathers in flight
  for (; base + 8 <= e; base += 8) {
    int p[8];
#pragma unroll
    for (int i = 0; i < 8; i++) p[i] = packed[base + i];
    uint2 v[8];
#pragma unroll
    for (int i = 0; i < 8; i++)
      v[i] = *(const uint2*)(x2 + (size_t)(p[i] & 0xFFFFF) * 128 + lane * 2);
    float4 w[8];
#pragma unroll
    for (int i = 0; i < 8; i++) w[i] = wt[p[i] >> 20];
#pragma unroll
    for (int i = 0; i < 8; i++) edge_fma(acc, v[i], w[i]);
  }

  // clamped tail (<= 7 edges, at most 2 iterations)
  for (; base < e; base += 4) {
    int rem = e - base;  // wave-uniform
    int i1 = base + (rem > 1 ? 1 : 0);
    int i2 = base + (rem > 2 ? 2 : 0);
    int i3 = base + (rem > 3 ? 3 : 0);
    int p0 = packed[base], p1 = packed[i1], p2 = packed[i2], p3 = packed[i3];
    uint2 v0 = *(const uint2*)(x2 + (size_t)(p0 & 0xFFFFF) * 128 + lane * 2);
    uint2 v1 = *(const uint2*)(x2 + (size_t)(p1 & 0xFFFFF) * 128 + lane * 2);
    uint2 v2 = *(const uint2*)(x2 + (size_t)(p2 & 0xFFFFF) * 128 + lane * 2);
    uint2 v3 = *(const uint2*)(x2 + (size_t)(p3 & 0xFFFFF) * 128 + lane * 2);
    float4 w0 = wt[p0 >> 20];
    float4 w1 = (rem > 1) ? wt[p1 >> 20] : wzero;
    float4 w2 = (rem > 2) ? wt[p2 >> 20] : wzero;
    float4 w3 = (rem > 3) ? wt[p3 >> 20] : wzero;
    edge_fma(acc, v0, w0);
    edge_fma(acc, v1, w1);
    edge_fma(acc, v2, w2);
    edge_fma(acc, v3, w3);
  }

  // store: k = (4*lane+j)*4 + b = 16*lane + 4*j + b -> 32 contiguous bytes
  union { short s[8]; int4 v; } u0, u1;
#pragma unroll
  for (int j = 0; j < 2; j++)
#pragma unroll
    for (int b = 0; b < BASES; b++) {
      u0.s[4 * j + b] = (short)f2bu(acc[b][j]);
      u1.s[4 * j + b] = (short)f2bu(acc[b][j + 2]);
    }
  __hip_bfloat16* zrow = zA + (size_t)n * KT;
  *(int4*)(zrow + 16 * lane) = u0.v;
  *(int4*)(zrow + 16 * lane + 8) = u1.v;

  // self block: straight bf16 copy of x2[n]
  uint2 sv = *(const uint2*)(x2 + (size_t)n * 128 + lane * 2);
  *(uint2*)((unsigned*)(zrow + BASES * D) + lane * 2) = sv;
}

// ---------------------------------------------------------------------------
// 7. GEMM: C[M,256] = A[M,1280](bf16) @ WT^T + bias. BM=64, BN=256 (full N,
//    A read once), 256 threads / 4 waves -> 782 blocks (~3/CU, balanced).
// ---------------------------------------------------------------------------
#define BM 64
#define BN 256
#define BK 32

template <bool RELU, typename OutT>
__global__ __launch_bounds__(256) void gemm_kernel(
    const __hip_bfloat16* __restrict__ A,   // [M, KT]
    const __hip_bfloat16* __restrict__ Bt,  // [256, KT] (transposed weights)
    const float* __restrict__ bias, OutT* __restrict__ C, int M) {
  __shared__ __align__(16) __hip_bfloat16 As[BM * BK];  // 4 KB
  __shared__ __align__(16) __hip_bfloat16 Bs[BN * BK];  // 16 KB
  int tid = threadIdx.x;
  int m0 = blockIdx.x * BM;
  int wave = tid >> 6, lane = tid & 63;
  int l15 = lane & 15, quad = lane >> 4;

  // staging geometry: one issue covers 16 rows; lane -> row base+lane/4,
  // col (lane&3)*8; LDS dest = wave-uniform base + lane*16 B
  int colS = (lane & 3) * 8;
  int r16  = lane >> 2;
  int grA  = min(m0 + wave * 16 + r16, M - 1);  // clamp; epilogue masks tail
  const __hip_bfloat16* gA = A + (size_t)grA * KT + colS;
  __hip_bfloat16* lA = As + wave * 512;
  const __hip_bfloat16* gB[4];
  __hip_bfloat16* lB[4];
#pragma unroll
  for (int c = 0; c < 4; c++) {
    gB[c] = Bt + (size_t)(wave * 64 + c * 16 + r16) * KT + colS;
    lB[c] = Bs + wave * 2048 + c * 512;
  }

  f32x4 acc[4][4] = {};

  for (int k0 = 0; k0 < KT; k0 += BK) {
    gload_lds16(lA, gA + k0);
#pragma unroll
    for (int c = 0; c < 4; c++) gload_lds16(lB[c], gB[c] + k0);
    __syncthreads();

    bf16x8 af[4], bfr[4];
#pragma unroll
    for (int mt = 0; mt < 4; mt++)
      af[mt] = *(const bf16x8*)(As + (mt * 16 + l15) * BK + quad * 8);
#pragma unroll
    for (int nt = 0; nt < 4; nt++)
      bfr[nt] = *(const bf16x8*)(Bs + (wave * 64 + nt * 16 + l15) * BK + quad * 8);
#pragma unroll
    for (int mt = 0; mt < 4; mt++)
#pragma unroll
      for (int nt = 0; nt < 4; nt++)
        acc[mt][nt] = __builtin_amdgcn_mfma_f32_16x16x32_bf16(
            af[mt], bfr[nt], acc[mt][nt], 0, 0, 0);
    __syncthreads();
  }

  // epilogue: C/D layout col = lane&15, row = quad*4 + reg
#pragma unroll
  for (int nt = 0; nt < 4; nt++) {
    int cg = wave * 64 + nt * 16 + l15;
    float bv = bias[cg];
#pragma unroll
    for (int mt = 0; mt < 4; mt++) {
#pragma unroll
      for (int r = 0; r < 4; r++) {
        int rg = m0 + mt * 16 + quad * 4 + r;
        if (rg < M) {
          float v = acc[mt][nt][r] + bv;
          if (RELU) v = fmaxf(v, 0.f);
          store_out(C + (size_t)rg * D + cg, v);
        }
      }
    }
  }
}

// ---------------------------------------------------------------------------
// Launch
// ---------------------------------------------------------------------------
static inline char* carve(char*& p, size_t bytes) {
  char* r = p;
  p += (bytes + 255) & ~(size_t)255;
  return r;
}

extern "C" void kernel_launch(void* const* d_in, const int* in_sizes, int n_in,
                              void* d_out, int out_size, void* d_ws,
                              size_t ws_size, hipStream_t stream) {
  const float* x      = (const float*)d_in[0];
  const int*   ei     = (const int*)d_in[1];
  const int*   et     = (const int*)d_in[2];
  const float* basis1 = (const float*)d_in[3];
  const float* comp1  = (const float*)d_in[4];
  const float* root1  = (const float*)d_in[5];
  const float* bias1  = (const float*)d_in[6];
  const float* basis2 = (const float*)d_in[7];
  const float* comp2  = (const float*)d_in[8];
  const float* root2  = (const float*)d_in[9];
  const float* bias2  = (const float*)d_in[10];
  float* out = (float*)d_out;

  char* ws = (char*)d_ws;
  int* cnt    = (int*)carve(ws, (size_t)NKEYS * 4);
  int* ecdf   = (int*)carve(ws, (size_t)(NKEYS + 1) * 4);
  int* rank   = (int*)carve(ws, (size_t)N_EDGES * 4);
  int* bsum   = (int*)carve(ws, (size_t)SCAN_B * 4);
  int* boff   = (int*)carve(ws, (size_t)SCAN_B * 4);
  int* packed = (int*)carve(ws, (size_t)N_EDGES * 4);
  float4* wtab1 = (float4*)carve(ws, (size_t)NKEYS * 16);
  float4* wtab2 = (float4*)carve(ws, (size_t)NKEYS * 16);
  __hip_bfloat16* WT1 = (__hip_bfloat16*)carve(ws, (size_t)D * KT * 2);
  __hip_bfloat16* WT2 = (__hip_bfloat16*)carve(ws, (size_t)D * KT * 2);
  unsigned* xb = (unsigned*)carve(ws, (size_t)N_NODES * D * 2);   // bf16 x
  __hip_bfloat16* h = (__hip_bfloat16*)carve(ws, (size_t)N_NODES * D * 2);
  __hip_bfloat16* zA = (__hip_bfloat16*)carve(ws, (size_t)N_NODES * KT * 2);

  const int EB = (N_EDGES + 255) / 256;   // 3125
  const int CB = (N_NODES * 128 + 255) / 256;

  hipMemsetAsync(cnt, 0, (size_t)NKEYS * 4, stream);

  count_rank_kernel<<<EB, 256, 0, stream>>>(ei, et, cnt, rank);
  scan_phaseA<<<SCAN_B, 256, 0, stream>>>(cnt, bsum);
  scan_phaseB<<<1, 256, 0, stream>>>(bsum, boff, ecdf);
  scan_phaseC_winv<<<SCAN_B, 256, 0, stream>>>(cnt, boff, comp1, comp2,
                                               ecdf, wtab1, wtab2);
  bucket_kernel<<<EB, 256, 0, stream>>>(ei, et, rank, ecdf, packed);

  convert_kernel<<<CB, 256, 0, stream>>>(x, xb);
  make_w_kernel<<<KT / 64, 256, 0, stream>>>(basis1, root1, WT1);
  make_w_kernel<<<KT / 64, 256, 0, stream>>>(basis2, root2, WT2);

  const int GB = (N_NODES + BM - 1) / BM;  // 782 blocks
  const int AB = (N_NODES + 3) / 4;        // 12500 blocks, wave per node

  // Layer 1
  aggregate_kernel<<<AB, 256, 0, stream>>>(xb, packed, ecdf, wtab1, zA);
  gemm_kernel<true, __hip_bfloat16><<<GB, 256, 0, stream>>>(zA, WT1, bias1, h, N_NODES);

  // Layer 2 (h is bf16 [N][256] — same packed-uint view as xb)
  aggregate_kernel<<<AB, 256, 0, stream>>>((const unsigned*)h, packed, ecdf, wtab2, zA);
  gemm_kernel<false, float><<<GB, 256, 0, stream>>>(zA, WT2, bias2, out, N_NODES);
}